// Round 1
// baseline (5787.429 us; speedup 1.0000x reference)
//
#include <hip/hip_runtime.h>
#include <hip/hip_bf16.h>
#include <math.h>

#define B_   2
#define T_   1024
#define H_   2048
#define NH_  8
#define NKV_ 2
#define HD_  256
#define S_   4
#define FF_  8192
#define LR_  64
#define ROWS_ (B_*T_)          // 2048 tokens
#define EPS_ 1e-6f

// ---------------- block-wide reductions (256 threads = 4 waves) ----------------
__device__ __forceinline__ float block_sum(float v) {
    __shared__ float s4[4];
    #pragma unroll
    for (int o = 32; o > 0; o >>= 1) v += __shfl_down(v, o, 64);
    int lane = threadIdx.x & 63;
    int w    = threadIdx.x >> 6;
    __syncthreads();                 // protect s4 across repeated calls
    if (lane == 0) s4[w] = v;
    __syncthreads();
    return s4[0] + s4[1] + s4[2] + s4[3];
}

__device__ __forceinline__ float block_max(float v) {
    __shared__ float s4m[4];
    #pragma unroll
    for (int o = 32; o > 0; o >>= 1) v = fmaxf(v, __shfl_down(v, o, 64));
    int lane = threadIdx.x & 63;
    int w    = threadIdx.x >> 6;
    __syncthreads();
    if (lane == 0) s4m[w] = v;
    __syncthreads();
    return fmaxf(fmaxf(s4m[0], s4m[1]), fmaxf(s4m[2], s4m[3]));
}

// ---------------- router: m = tanh( (LN(x)*w_norm / H) @ router_w^T ) ----------
__global__ __launch_bounds__(256) void router_kernel(
    const float* __restrict__ x, const float* __restrict__ nw,
    const float* __restrict__ rw, float* __restrict__ mout)
{
    size_t row = blockIdx.x;
    int tid = threadIdx.x;
    const float* xr = x + row * H_;
    float v[8]; float s = 0.f;
    #pragma unroll
    for (int i = 0; i < 8; ++i) { v[i] = xr[i*256 + tid]; s += v[i]; }
    float mu = block_sum(s) * (1.f / H_);
    float ss = 0.f;
    #pragma unroll
    for (int i = 0; i < 8; ++i) { float c = v[i] - mu; ss += c * c; }
    float rstd = rsqrtf(block_sum(ss) * (1.f / H_) + EPS_);
    float n[8];
    #pragma unroll
    for (int i = 0; i < 8; ++i) n[i] = (v[i] - mu) * rstd * nw[i*256 + tid];
    for (int so = 0; so < S_; ++so) {
        float p = 0.f;
        #pragma unroll
        for (int i = 0; i < 8; ++i) p += n[i] * rw[(size_t)so * H_ + i*256 + tid];
        float dot = block_sum(p);
        if (tid == 0) mout[row * S_ + so] = tanhf(dot * (1.f / H_));
    }
}

// ---------------- altup predict ----------------
__global__ __launch_bounds__(256) void predict_kernel(
    const float* __restrict__ hid, const float* __restrict__ m,
    const float* __restrict__ pcw, float* __restrict__ pred)
{
    size_t row = blockIdx.x;
    int tid = threadIdx.x;
    __shared__ float ms[4];
    __shared__ float c[16];
    if (tid < 4) ms[tid] = m[row * S_ + tid];
    __syncthreads();
    if (tid < 16) {
        float s = 0.f;
        #pragma unroll
        for (int i = 0; i < 4; ++i) s += ms[i] * pcw[tid * 4 + i];
        c[tid] = s;
    }
    __syncthreads();
    const size_t STRIDE = (size_t)ROWS_ * H_;      // 4,194,304
    #pragma unroll
    for (int i = 0; i < 8; ++i) {
        size_t idx = row * H_ + i*256 + tid;
        float h0 = hid[idx];
        float h1 = hid[idx + STRIDE];
        float h2 = hid[idx + 2*STRIDE];
        float h3 = hid[idx + 3*STRIDE];
        float hv[4] = {h0, h1, h2, h3};
        #pragma unroll
        for (int j = 0; j < 4; ++j) {
            float val = hv[j] + h0*c[j*4+0] + h1*c[j*4+1] + h2*c[j*4+2] + h3*c[j*4+3];
            pred[idx + (size_t)j * STRIDE] = val;
        }
    }
}

// ---------------- LN (+ optional residual adds, + scale), H=2048 ----------------
__global__ __launch_bounds__(256) void ln_residual(
    const float* __restrict__ x, const float* __restrict__ w,
    const float* __restrict__ a1, const float* __restrict__ a2,
    float scale, float* __restrict__ out)
{
    size_t row = blockIdx.x;
    int tid = threadIdx.x;
    const float* xr = x + row * H_;
    float v[8]; float s = 0.f;
    #pragma unroll
    for (int i = 0; i < 8; ++i) { v[i] = xr[i*256 + tid]; s += v[i]; }
    float mu = block_sum(s) * (1.f / H_);
    float ss = 0.f;
    #pragma unroll
    for (int i = 0; i < 8; ++i) { float c = v[i] - mu; ss += c * c; }
    float rstd = rsqrtf(block_sum(ss) * (1.f / H_) + EPS_);
    #pragma unroll
    for (int i = 0; i < 8; ++i) {
        size_t idx = row * H_ + i*256 + tid;
        float y = (v[i] - mu) * rstd * w[i*256 + tid];
        if (a1) y += a1[idx];
        if (a2) y += a2[idx];
        out[idx] = y * scale;
    }
}

// ---------------- GEMM: C[M,N] = A[M,K] * B[N,K]^T (both row-major over K) ------
#define BM 64
#define BN 64
#define BK 32
#define LDP 68   // pad: keeps float4 alignment (68%4==0), reduces store conflicts

__global__ __launch_bounds__(256) void gemm_nt(
    const float* __restrict__ A, const float* __restrict__ Bm,
    float* __restrict__ C, int M, int N, int K)
{
    __shared__ float As[BK][LDP];
    __shared__ float Bs[BK][LDP];
    int tid = threadIdx.x;
    int n0 = blockIdx.x * BN;
    int m0 = blockIdx.y * BM;
    int tx = tid & 15, ty = tid >> 4;
    int lrow = tid >> 3;            // 0..31
    int lk   = (tid & 7) << 2;      // 0,4,...,28
    float acc[4][4] = {};
    for (int k0 = 0; k0 < K; k0 += BK) {
        #pragma unroll
        for (int r = 0; r < 2; ++r) {
            int row = lrow + r * 32;
            float4 a4 = *reinterpret_cast<const float4*>(&A[(size_t)(m0 + row) * K + k0 + lk]);
            As[lk+0][row] = a4.x; As[lk+1][row] = a4.y; As[lk+2][row] = a4.z; As[lk+3][row] = a4.w;
            float4 b4 = *reinterpret_cast<const float4*>(&Bm[(size_t)(n0 + row) * K + k0 + lk]);
            Bs[lk+0][row] = b4.x; Bs[lk+1][row] = b4.y; Bs[lk+2][row] = b4.z; Bs[lk+3][row] = b4.w;
        }
        __syncthreads();
        #pragma unroll
        for (int k = 0; k < BK; ++k) {
            float4 av = *reinterpret_cast<const float4*>(&As[k][ty << 2]);
            float4 bv = *reinterpret_cast<const float4*>(&Bs[k][tx << 2]);
            float a[4] = {av.x, av.y, av.z, av.w};
            float b[4] = {bv.x, bv.y, bv.z, bv.w};
            #pragma unroll
            for (int i = 0; i < 4; ++i)
                #pragma unroll
                for (int j = 0; j < 4; ++j)
                    acc[i][j] = fmaf(a[i], b[j], acc[i][j]);
        }
        __syncthreads();
    }
    #pragma unroll
    for (int i = 0; i < 4; ++i) {
        float4 o; o.x = acc[i][0]; o.y = acc[i][1]; o.z = acc[i][2]; o.w = acc[i][3];
        *reinterpret_cast<float4*>(&C[(size_t)(m0 + (ty << 2) + i) * N + n0 + (tx << 2)]) = o;
    }
}

// ---------------- fused gate/up GEMM: C = gelu_tanh(A*G^T) * (A*U^T) ------------
__global__ __launch_bounds__(256) void gemm_gateup(
    const float* __restrict__ A, const float* __restrict__ G,
    const float* __restrict__ U, float* __restrict__ C, int M, int N, int K)
{
    __shared__ float As[BK][LDP];
    __shared__ float Gs[BK][LDP];
    __shared__ float Us[BK][LDP];
    int tid = threadIdx.x;
    int n0 = blockIdx.x * BN;
    int m0 = blockIdx.y * BM;
    int tx = tid & 15, ty = tid >> 4;
    int lrow = tid >> 3;
    int lk   = (tid & 7) << 2;
    float accg[4][4] = {};
    float accu[4][4] = {};
    for (int k0 = 0; k0 < K; k0 += BK) {
        #pragma unroll
        for (int r = 0; r < 2; ++r) {
            int row = lrow + r * 32;
            float4 a4 = *reinterpret_cast<const float4*>(&A[(size_t)(m0 + row) * K + k0 + lk]);
            As[lk+0][row] = a4.x; As[lk+1][row] = a4.y; As[lk+2][row] = a4.z; As[lk+3][row] = a4.w;
            float4 g4 = *reinterpret_cast<const float4*>(&G[(size_t)(n0 + row) * K + k0 + lk]);
            Gs[lk+0][row] = g4.x; Gs[lk+1][row] = g4.y; Gs[lk+2][row] = g4.z; Gs[lk+3][row] = g4.w;
            float4 u4 = *reinterpret_cast<const float4*>(&U[(size_t)(n0 + row) * K + k0 + lk]);
            Us[lk+0][row] = u4.x; Us[lk+1][row] = u4.y; Us[lk+2][row] = u4.z; Us[lk+3][row] = u4.w;
        }
        __syncthreads();
        #pragma unroll
        for (int k = 0; k < BK; ++k) {
            float4 av = *reinterpret_cast<const float4*>(&As[k][ty << 2]);
            float4 gv = *reinterpret_cast<const float4*>(&Gs[k][tx << 2]);
            float4 uv = *reinterpret_cast<const float4*>(&Us[k][tx << 2]);
            float a[4] = {av.x, av.y, av.z, av.w};
            float g[4] = {gv.x, gv.y, gv.z, gv.w};
            float u[4] = {uv.x, uv.y, uv.z, uv.w};
            #pragma unroll
            for (int i = 0; i < 4; ++i)
                #pragma unroll
                for (int j = 0; j < 4; ++j) {
                    accg[i][j] = fmaf(a[i], g[j], accg[i][j]);
                    accu[i][j] = fmaf(a[i], u[j], accu[i][j]);
                }
        }
        __syncthreads();
    }
    #pragma unroll
    for (int i = 0; i < 4; ++i) {
        float4 o;
        float* op = &o.x;
        #pragma unroll
        for (int j = 0; j < 4; ++j) {
            float g = accg[i][j];
            float gel = 0.5f * g * (1.f + tanhf(0.7978845608028654f * (g + 0.044715f * g * g * g)));
            op[j] = gel * accu[i][j];
        }
        *reinterpret_cast<float4*>(&C[(size_t)(m0 + (ty << 2) + i) * N + n0 + (tx << 2)]) = o;
    }
}

// ---------------- per-head LN (+optional RoPE) and transpose to [B,nh,T,HD] -----
__global__ __launch_bounds__(256) void qkv_norm_rope(
    const float* __restrict__ in, const float* __restrict__ w,
    const float* __restrict__ cs, const float* __restrict__ sn,
    float* __restrict__ out, int nh, int do_rope)
{
    int blk = blockIdx.x;
    int h = blk % nh;
    int trow = blk / nh;           // b*T + t
    int b = trow / T_;
    int t = trow % T_;
    int d = threadIdx.x;           // 0..255 == HD
    float x = in[((size_t)trow * nh + h) * HD_ + d];
    float mu = block_sum(x) * (1.f / HD_);
    float xc = x - mu;
    float var = block_sum(xc * xc) * (1.f / HD_);
    float n = xc * rsqrtf(var + EPS_) * (w ? w[d] : 1.f);
    __shared__ float buf[HD_];
    buf[d] = n;
    __syncthreads();
    float val = n;
    if (do_rope) {
        float c = cs[(size_t)trow * HD_ + d];
        float s = sn[(size_t)trow * HD_ + d];
        float other = (d < 128) ? -buf[d + 128] : buf[d - 128];
        val = n * c + other * s;
    }
    out[(((size_t)b * nh + h) * T_ + t) * HD_ + d] = val;
}

// ---------------- causal attention, one block per (b,h,q-row) -------------------
__global__ __launch_bounds__(256) void attn_kernel(
    const float* __restrict__ qt, const float* __restrict__ kt,
    const float* __restrict__ vt, float* __restrict__ out)
{
    int blk = blockIdx.x;
    int qi = blk % T_;
    int bh = blk / T_;
    int h = bh % NH_;
    int b = bh / NH_;
    int kvh = h >> 2;              // rep = NH/NKV = 4
    int tid = threadIdx.x;
    __shared__ float qs[HD_];
    __shared__ float sc[T_];
    __shared__ float ks[32][257];
    __shared__ float red[8][32];
    const float* qrow = qt + (((size_t)b * NH_ + h) * T_ + qi) * HD_;
    qs[tid] = qrow[tid];
    const float* Kb = kt + ((size_t)b * NKV_ + kvh) * T_ * HD_;
    const float* Vb = vt + ((size_t)b * NKV_ + kvh) * T_ * HD_;
    int L = qi + 1;
    __syncthreads();

    for (int kb = 0; kb < L; kb += 32) {
        int rows = min(32, L - kb);
        for (int u = 0; u < 32; ++u)
            if (u < rows) ks[u][tid] = Kb[(size_t)(kb + u) * HD_ + tid];
        __syncthreads();
        int kl = tid & 31, ch = tid >> 5;   // 32 k-rows x 8 d-chunks
        float p = 0.f;
        if (kl < rows) {
            #pragma unroll
            for (int i = 0; i < 32; ++i) p += qs[ch * 32 + i] * ks[kl][ch * 32 + i];
        }
        red[ch][kl] = p;
        __syncthreads();
        if (tid < rows) {
            float s = 0.f;
            #pragma unroll
            for (int c = 0; c < 8; ++c) s += red[c][tid];
            sc[kb + tid] = s;
        }
        __syncthreads();
    }

    float mx = -3.402823466e38f;
    for (int k2 = tid; k2 < L; k2 += 256) mx = fmaxf(mx, sc[k2]);
    mx = block_max(mx);
    float sm = 0.f;
    for (int k2 = tid; k2 < L; k2 += 256) { float e = expf(sc[k2] - mx); sc[k2] = e; sm += e; }
    sm = block_sum(sm);
    float inv = 1.f / sm;
    float acc = 0.f;
    for (int k2 = 0; k2 < L; ++k2) acc += sc[k2] * Vb[(size_t)k2 * HD_ + tid];
    // write in [B,T,NH,HD] so the WO GEMM sees reshape(B,T,NH*HD)
    out[(((size_t)b * T_ + qi) * NH_ + h) * HD_ + tid] = acc * inv;
}

// ---------------- altup correct + output-scale on stream 0 ----------------------
__global__ __launch_bounds__(256) void correct_kernel(
    const float* __restrict__ act, const float* __restrict__ pred,
    const float* __restrict__ mc, const float* __restrict__ ccw,
    const float* __restrict__ cscale, float* __restrict__ out)
{
    size_t row = blockIdx.x;
    int tid = threadIdx.x;
    __shared__ float ms[4];
    __shared__ float cc[4];
    if (tid < 4) ms[tid] = mc[row * S_ + tid];
    __syncthreads();
    if (tid < 4) {
        float s = 1.f;
        #pragma unroll
        for (int i = 0; i < 4; ++i) s += ms[i] * ccw[tid * 4 + i];
        cc[tid] = s;
    }
    __syncthreads();
    const size_t STRIDE = (size_t)ROWS_ * H_;
    #pragma unroll
    for (int i = 0; i < 8; ++i) {
        size_t idx = row * H_ + i*256 + tid;
        float a  = act[idx];
        float p0 = pred[idx];
        float inn = a - p0;
        #pragma unroll
        for (int j = 0; j < 4; ++j) {
            float val = inn * cc[j] + pred[idx + (size_t)j * STRIDE];
            if (j == 0) val *= cscale[i*256 + tid];
            out[idx + (size_t)j * STRIDE] = val;
        }
    }
}

// ---------------- launcher ----------------
extern "C" void kernel_launch(void* const* d_in, const int* in_sizes, int n_in,
                              void* d_out, int out_size, void* d_ws, size_t ws_size,
                              hipStream_t stream)
{
    (void)in_sizes; (void)n_in; (void)out_size; (void)ws_size;
    const float* hidden         = (const float*)d_in[0];
    const float* cosp           = (const float*)d_in[1];
    const float* sinp           = (const float*)d_in[2];
    const float* wq             = (const float*)d_in[3];
    const float* wk             = (const float*)d_in[4];
    const float* wv             = (const float*)d_in[5];
    const float* wo             = (const float*)d_in[6];
    const float* q_norm_w       = (const float*)d_in[7];
    const float* k_norm_w       = (const float*)d_in[8];
    const float* input_ln_w     = (const float*)d_in[9];
    const float* post_attn_ln_w = (const float*)d_in[10];
    const float* pre_ffw_ln_w   = (const float*)d_in[11];
    const float* post_ffw_ln_w  = (const float*)d_in[12];
    const float* gate_w         = (const float*)d_in[13];
    const float* up_w           = (const float*)d_in[14];
    const float* down_w         = (const float*)d_in[15];
    const float* ll_w           = (const float*)d_in[16];
    const float* lr_w           = (const float*)d_in[17];
    const float* laurel_norm_w  = (const float*)d_in[18];
    const float* router_norm_w  = (const float*)d_in[19];
    const float* router_w       = (const float*)d_in[20];
    const float* pred_coef_w    = (const float*)d_in[21];
    const float* corr_coef_w    = (const float*)d_in[22];
    const float* cscale         = (const float*)d_in[23];
    float* outp = (float*)d_out;

    float* ws = (float*)d_ws;
    size_t off = 0;
    float* pred  = ws + off; off += (size_t)S_ * ROWS_ * H_;   // 16,777,216 (live to end)
    float* W1    = ws + off; off += (size_t)ROWS_ * FF_;       // 16,777,216 (qkv arena -> gu)
    float* xnorm = ws + off; off += (size_t)ROWS_ * H_;        // x_norm -> h_ffw
    float* lout  = ws + off; off += (size_t)ROWS_ * H_;        // laurel_out -> activated
    float* alaur = ws + off; off += (size_t)ROWS_ * H_;        // attn_laurel
    float* tmpH  = ws + off; off += (size_t)ROWS_ * H_;        // generic [rows,H] temp
    float* mbuf  = ws + off; off += (size_t)ROWS_ * S_;
    float* mcbuf = ws + off; off += (size_t)ROWS_ * S_;
    float* ltmp  = ws + off; off += (size_t)ROWS_ * LR_;       // total ~202 MB

    float* q_pre = W1;
    float* k_pre = W1 + 4194304;
    float* v_pre = W1 + 5242880;
    float* q_t   = W1 + 6291456;
    float* k_t   = W1 + 10485760;
    float* v_t   = W1 + 11534336;
    float* attn_out  = W1;      // reuse q_pre slot (dead after norm/rope)
    float* gu        = W1;      // whole arena free after WO GEMM
    float* activated = lout;    // laurel_out dead after attn_laurel fuse

    // ---- AltUp predict ----
    router_kernel <<<ROWS_, 256, 0, stream>>>(hidden, router_norm_w, router_w, mbuf);
    predict_kernel<<<ROWS_, 256, 0, stream>>>(hidden, mbuf, pred_coef_w, pred);
    ln_residual   <<<ROWS_, 256, 0, stream>>>(pred, input_ln_w, nullptr, nullptr, 1.f, xnorm);

    // ---- Laurel ----
    gemm_nt<<<dim3(LR_/BN, ROWS_/BM), 256, 0, stream>>>(xnorm, ll_w, ltmp, ROWS_, LR_, H_);
    gemm_nt<<<dim3(H_/BN,  ROWS_/BM), 256, 0, stream>>>(ltmp, lr_w, tmpH, ROWS_, H_, LR_);
    ln_residual<<<ROWS_, 256, 0, stream>>>(tmpH, laurel_norm_w, xnorm, nullptr, 1.f, lout);

    // ---- Attention ----
    gemm_nt<<<dim3((NH_*HD_)/BN,  ROWS_/BM), 256, 0, stream>>>(xnorm, wq, q_pre, ROWS_, NH_*HD_,  H_);
    gemm_nt<<<dim3((NKV_*HD_)/BN, ROWS_/BM), 256, 0, stream>>>(xnorm, wk, k_pre, ROWS_, NKV_*HD_, H_);
    gemm_nt<<<dim3((NKV_*HD_)/BN, ROWS_/BM), 256, 0, stream>>>(xnorm, wv, v_pre, ROWS_, NKV_*HD_, H_);
    qkv_norm_rope<<<ROWS_*NH_,  256, 0, stream>>>(q_pre, q_norm_w, cosp, sinp, q_t, NH_,  1);
    qkv_norm_rope<<<ROWS_*NKV_, 256, 0, stream>>>(k_pre, k_norm_w, cosp, sinp, k_t, NKV_, 1);
    qkv_norm_rope<<<ROWS_*NKV_, 256, 0, stream>>>(v_pre, nullptr,  cosp, sinp, v_t, NKV_, 0);
    attn_kernel<<<B_*NH_*T_, 256, 0, stream>>>(q_t, k_t, v_t, attn_out);
    gemm_nt<<<dim3(H_/BN, ROWS_/BM), 256, 0, stream>>>(attn_out, wo, tmpH, ROWS_, H_, NH_*HD_);
    // attn_laurel = (active + LN(attn) + laurel_out) / sqrt(2)
    ln_residual<<<ROWS_, 256, 0, stream>>>(tmpH, post_attn_ln_w, pred, lout, 0.7071067811865475f, alaur);

    // ---- MLP ----
    ln_residual<<<ROWS_, 256, 0, stream>>>(alaur, pre_ffw_ln_w, nullptr, nullptr, 1.f, xnorm);
    gemm_gateup<<<dim3(FF_/BN, ROWS_/BM), 256, 0, stream>>>(xnorm, gate_w, up_w, gu, ROWS_, FF_, H_);
    gemm_nt<<<dim3(H_/BN, ROWS_/BM), 256, 0, stream>>>(gu, down_w, tmpH, ROWS_, H_, FF_);
    ln_residual<<<ROWS_, 256, 0, stream>>>(tmpH, post_ffw_ln_w, alaur, nullptr, 1.f, activated);

    // ---- AltUp correct ----
    router_kernel <<<ROWS_, 256, 0, stream>>>(activated, router_norm_w, router_w, mcbuf);
    correct_kernel<<<ROWS_, 256, 0, stream>>>(activated, pred, mcbuf, corr_coef_w, cscale, outp);
}

// Round 2
// 2602.664 us; speedup vs baseline: 2.2237x; 2.2237x over previous
//
#include <hip/hip_runtime.h>
#include <hip/hip_bf16.h>
#include <math.h>

#define B_   2
#define T_   1024
#define H_   2048
#define NH_  8
#define NKV_ 2
#define HD_  256
#define S_   4
#define FF_  8192
#define LR_  64
#define ROWS_ (B_*T_)          // 2048 tokens
#define EPS_ 1e-6f

typedef __attribute__((ext_vector_type(8))) __bf16 bf16x8;
typedef __attribute__((ext_vector_type(4))) float floatx4;
typedef __attribute__((ext_vector_type(8))) unsigned short ushort8v;

__device__ __forceinline__ unsigned short f2bf(float f) {
    unsigned int u = __float_as_uint(f);
    return (unsigned short)((u + 0x7FFFu + ((u >> 16) & 1u)) >> 16);
}

// ---------------- block-wide reductions (256 threads = 4 waves) ----------------
__device__ __forceinline__ float block_sum(float v) {
    __shared__ float s4[4];
    #pragma unroll
    for (int o = 32; o > 0; o >>= 1) v += __shfl_down(v, o, 64);
    int lane = threadIdx.x & 63;
    int w    = threadIdx.x >> 6;
    __syncthreads();
    if (lane == 0) s4[w] = v;
    __syncthreads();
    return s4[0] + s4[1] + s4[2] + s4[3];
}

__device__ __forceinline__ float block_max(float v) {
    __shared__ float s4m[4];
    #pragma unroll
    for (int o = 32; o > 0; o >>= 1) v = fmaxf(v, __shfl_down(v, o, 64));
    int lane = threadIdx.x & 63;
    int w    = threadIdx.x >> 6;
    __syncthreads();
    if (lane == 0) s4m[w] = v;
    __syncthreads();
    return fmaxf(fmaxf(s4m[0], s4m[1]), fmaxf(s4m[2], s4m[3]));
}

// ---------------- fp32 -> bf16 convert (8 elements/thread) ----------------------
__global__ __launch_bounds__(256) void cvt_bf16(
    const float* __restrict__ in, unsigned short* __restrict__ out, int n)
{
    int i = (blockIdx.x * 256 + threadIdx.x) * 8;
    if (i >= n) return;
    float4 v0 = *reinterpret_cast<const float4*>(in + i);
    float4 v1 = *reinterpret_cast<const float4*>(in + i + 4);
    ushort8v o;
    o[0] = f2bf(v0.x); o[1] = f2bf(v0.y); o[2] = f2bf(v0.z); o[3] = f2bf(v0.w);
    o[4] = f2bf(v1.x); o[5] = f2bf(v1.y); o[6] = f2bf(v1.z); o[7] = f2bf(v1.w);
    *reinterpret_cast<ushort8v*>(out + i) = o;
}

// ---------------- router: m = tanh( (LN(x)*w_norm / H) @ router_w^T ) ----------
__global__ __launch_bounds__(256) void router_kernel(
    const float* __restrict__ x, const float* __restrict__ nw,
    const float* __restrict__ rw, float* __restrict__ mout)
{
    size_t row = blockIdx.x;
    int tid = threadIdx.x;
    const float* xr = x + row * H_;
    float v[8]; float s = 0.f;
    #pragma unroll
    for (int i = 0; i < 8; ++i) { v[i] = xr[i*256 + tid]; s += v[i]; }
    float mu = block_sum(s) * (1.f / H_);
    float ss = 0.f;
    #pragma unroll
    for (int i = 0; i < 8; ++i) { float c = v[i] - mu; ss += c * c; }
    float rstd = rsqrtf(block_sum(ss) * (1.f / H_) + EPS_);
    float n[8];
    #pragma unroll
    for (int i = 0; i < 8; ++i) n[i] = (v[i] - mu) * rstd * nw[i*256 + tid];
    for (int so = 0; so < S_; ++so) {
        float p = 0.f;
        #pragma unroll
        for (int i = 0; i < 8; ++i) p += n[i] * rw[(size_t)so * H_ + i*256 + tid];
        float dot = block_sum(p);
        if (tid == 0) mout[row * S_ + so] = tanhf(dot * (1.f / H_));
    }
}

// ---------------- altup predict ----------------
__global__ __launch_bounds__(256) void predict_kernel(
    const float* __restrict__ hid, const float* __restrict__ m,
    const float* __restrict__ pcw, float* __restrict__ pred)
{
    size_t row = blockIdx.x;
    int tid = threadIdx.x;
    __shared__ float ms[4];
    __shared__ float c[16];
    if (tid < 4) ms[tid] = m[row * S_ + tid];
    __syncthreads();
    if (tid < 16) {
        float s = 0.f;
        #pragma unroll
        for (int i = 0; i < 4; ++i) s += ms[i] * pcw[tid * 4 + i];
        c[tid] = s;
    }
    __syncthreads();
    const size_t STRIDE = (size_t)ROWS_ * H_;
    #pragma unroll
    for (int i = 0; i < 8; ++i) {
        size_t idx = row * H_ + i*256 + tid;
        float h0 = hid[idx];
        float h1 = hid[idx + STRIDE];
        float h2 = hid[idx + 2*STRIDE];
        float h3 = hid[idx + 3*STRIDE];
        float hv[4] = {h0, h1, h2, h3};
        #pragma unroll
        for (int j = 0; j < 4; ++j) {
            float val = hv[j] + h0*c[j*4+0] + h1*c[j*4+1] + h2*c[j*4+2] + h3*c[j*4+3];
            pred[idx + (size_t)j * STRIDE] = val;
        }
    }
}

// ---------------- LN (+ optional residuals, scale, fp32 and/or bf16 out) --------
__global__ __launch_bounds__(256) void ln_residual(
    const float* __restrict__ x, const float* __restrict__ w,
    const float* __restrict__ a1, const float* __restrict__ a2,
    float scale, float* __restrict__ out, unsigned short* __restrict__ outb)
{
    size_t row = blockIdx.x;
    int tid = threadIdx.x;
    const float* xr = x + row * H_;
    float v[8]; float s = 0.f;
    #pragma unroll
    for (int i = 0; i < 8; ++i) { v[i] = xr[i*256 + tid]; s += v[i]; }
    float mu = block_sum(s) * (1.f / H_);
    float ss = 0.f;
    #pragma unroll
    for (int i = 0; i < 8; ++i) { float c = v[i] - mu; ss += c * c; }
    float rstd = rsqrtf(block_sum(ss) * (1.f / H_) + EPS_);
    #pragma unroll
    for (int i = 0; i < 8; ++i) {
        size_t idx = row * H_ + i*256 + tid;
        float y = (v[i] - mu) * rstd * w[i*256 + tid];
        if (a1) y += a1[idx];
        if (a2) y += a2[idx];
        y *= scale;
        if (out)  out[idx]  = y;
        if (outb) outb[idx] = f2bf(y);
    }
}

// ---------------- fp32 GEMM (laurel only): C = A[M,K] * B[N,K]^T ----------------
#define BM 64
#define BN 64
#define BK 32
#define LDP 68

__global__ __launch_bounds__(256) void gemm_nt(
    const float* __restrict__ A, const float* __restrict__ Bm,
    float* __restrict__ C, int M, int N, int K)
{
    __shared__ float As[BK][LDP];
    __shared__ float Bs[BK][LDP];
    int tid = threadIdx.x;
    int n0 = blockIdx.x * BN;
    int m0 = blockIdx.y * BM;
    int tx = tid & 15, ty = tid >> 4;
    int lrow = tid >> 3;
    int lk   = (tid & 7) << 2;
    float acc[4][4] = {};
    for (int k0 = 0; k0 < K; k0 += BK) {
        #pragma unroll
        for (int r = 0; r < 2; ++r) {
            int row = lrow + r * 32;
            float4 a4 = *reinterpret_cast<const float4*>(&A[(size_t)(m0 + row) * K + k0 + lk]);
            As[lk+0][row] = a4.x; As[lk+1][row] = a4.y; As[lk+2][row] = a4.z; As[lk+3][row] = a4.w;
            float4 b4 = *reinterpret_cast<const float4*>(&Bm[(size_t)(n0 + row) * K + k0 + lk]);
            Bs[lk+0][row] = b4.x; Bs[lk+1][row] = b4.y; Bs[lk+2][row] = b4.z; Bs[lk+3][row] = b4.w;
        }
        __syncthreads();
        #pragma unroll
        for (int k = 0; k < BK; ++k) {
            float4 av = *reinterpret_cast<const float4*>(&As[k][ty << 2]);
            float4 bv = *reinterpret_cast<const float4*>(&Bs[k][tx << 2]);
            float a[4] = {av.x, av.y, av.z, av.w};
            float b[4] = {bv.x, bv.y, bv.z, bv.w};
            #pragma unroll
            for (int i = 0; i < 4; ++i)
                #pragma unroll
                for (int j = 0; j < 4; ++j)
                    acc[i][j] = fmaf(a[i], b[j], acc[i][j]);
        }
        __syncthreads();
    }
    #pragma unroll
    for (int i = 0; i < 4; ++i) {
        float4 o; o.x = acc[i][0]; o.y = acc[i][1]; o.z = acc[i][2]; o.w = acc[i][3];
        *reinterpret_cast<float4*>(&C[(size_t)(m0 + (ty << 2) + i) * N + n0 + (tx << 2)]) = o;
    }
}

// ---------------- bf16 MFMA GEMM: C_fp32[M,N] = A_bf16[M,K] * B_bf16[N,K]^T -----
// 128x128 tile, BK=32, 4 waves each 64x64, LDS chunk-major [kc][row][8]
__global__ __launch_bounds__(256) void gemm_bf16nt(
    const unsigned short* __restrict__ A, const unsigned short* __restrict__ Bm,
    float* __restrict__ C, int M, int N, int K)
{
    __shared__ unsigned short As[4096];   // [kc:4][m:128][8]
    __shared__ unsigned short Bs[4096];
    int tid = threadIdx.x;
    int lane = tid & 63;
    int wave = tid >> 6;
    int m0 = blockIdx.y * 128, n0 = blockIdx.x * 128;
    int wm = (wave >> 1) * 64;
    int wn = (wave & 1) * 64;
    floatx4 acc[4][4] = {};

    int cm = tid >> 2;        // 0..63
    int ck = tid & 3;         // k-chunk
    const unsigned short* aP0 = A  + (size_t)(m0 + cm)      * K + ck * 8;
    const unsigned short* aP1 = A  + (size_t)(m0 + 64 + cm) * K + ck * 8;
    const unsigned short* bP0 = Bm + (size_t)(n0 + cm)      * K + ck * 8;
    const unsigned short* bP1 = Bm + (size_t)(n0 + 64 + cm) * K + ck * 8;
    unsigned short* aW0 = &As[(ck * 128 + cm) * 8];
    unsigned short* aW1 = &As[(ck * 128 + 64 + cm) * 8];
    unsigned short* bW0 = &Bs[(ck * 128 + cm) * 8];
    unsigned short* bW1 = &Bs[(ck * 128 + 64 + cm) * 8];

    uint4 ra0 = *reinterpret_cast<const uint4*>(aP0);
    uint4 ra1 = *reinterpret_cast<const uint4*>(aP1);
    uint4 rb0 = *reinterpret_cast<const uint4*>(bP0);
    uint4 rb1 = *reinterpret_cast<const uint4*>(bP1);

    int kc = lane >> 4, mr = lane & 15;
    for (int k0 = 0; k0 < K; k0 += 32) {
        __syncthreads();
        *reinterpret_cast<uint4*>(aW0) = ra0;
        *reinterpret_cast<uint4*>(aW1) = ra1;
        *reinterpret_cast<uint4*>(bW0) = rb0;
        *reinterpret_cast<uint4*>(bW1) = rb1;
        __syncthreads();
        if (k0 + 32 < K) {
            ra0 = *reinterpret_cast<const uint4*>(aP0 + k0 + 32);
            ra1 = *reinterpret_cast<const uint4*>(aP1 + k0 + 32);
            rb0 = *reinterpret_cast<const uint4*>(bP0 + k0 + 32);
            rb1 = *reinterpret_cast<const uint4*>(bP1 + k0 + 32);
        }
        bf16x8 af[4], bfv[4];
        #pragma unroll
        for (int mi = 0; mi < 4; ++mi)
            af[mi] = *reinterpret_cast<const bf16x8*>(&As[kc * 1024 + (wm + mi * 16 + mr) * 8]);
        #pragma unroll
        for (int ni = 0; ni < 4; ++ni)
            bfv[ni] = *reinterpret_cast<const bf16x8*>(&Bs[kc * 1024 + (wn + ni * 16 + mr) * 8]);
        #pragma unroll
        for (int mi = 0; mi < 4; ++mi)
            #pragma unroll
            for (int ni = 0; ni < 4; ++ni)
                acc[mi][ni] = __builtin_amdgcn_mfma_f32_16x16x32_bf16(af[mi], bfv[ni], acc[mi][ni], 0, 0, 0);
    }
    int quad = lane >> 4;
    #pragma unroll
    for (int mi = 0; mi < 4; ++mi)
        #pragma unroll
        for (int ni = 0; ni < 4; ++ni)
            #pragma unroll
            for (int r = 0; r < 4; ++r)
                C[(size_t)(m0 + wm + mi * 16 + quad * 4 + r) * N + n0 + wn + ni * 16 + mr] = acc[mi][ni][r];
}

// ---------------- fused gate/up bf16 GEMM -> gu_bf16 = gelu(A*G^T)*(A*U^T) ------
// BM=128, BN=64, BK=32; 4 waves each 32 rows x 64 cols
__global__ __launch_bounds__(256) void gemm_gateup_bf16(
    const unsigned short* __restrict__ A, const unsigned short* __restrict__ G,
    const unsigned short* __restrict__ U, unsigned short* __restrict__ Cbf,
    int M, int N, int K)
{
    __shared__ unsigned short As[4096];  // [kc:4][m:128][8]
    __shared__ unsigned short Gs[2048];  // [kc:4][n:64][8]
    __shared__ unsigned short Us[2048];
    int tid = threadIdx.x;
    int lane = tid & 63;
    int wave = tid >> 6;
    int m0 = blockIdx.y * 128, n0 = blockIdx.x * 64;
    floatx4 accg[2][4] = {};
    floatx4 accu[2][4] = {};

    int cm = tid >> 2;
    int ck = tid & 3;
    const unsigned short* aP0 = A + (size_t)(m0 + cm)      * K + ck * 8;
    const unsigned short* aP1 = A + (size_t)(m0 + 64 + cm) * K + ck * 8;
    const unsigned short* gP  = G + (size_t)(n0 + cm)      * K + ck * 8;
    const unsigned short* uP  = U + (size_t)(n0 + cm)      * K + ck * 8;
    unsigned short* aW0 = &As[(ck * 128 + cm) * 8];
    unsigned short* aW1 = &As[(ck * 128 + 64 + cm) * 8];
    unsigned short* gW  = &Gs[(ck * 64 + cm) * 8];
    unsigned short* uW  = &Us[(ck * 64 + cm) * 8];

    uint4 ra0 = *reinterpret_cast<const uint4*>(aP0);
    uint4 ra1 = *reinterpret_cast<const uint4*>(aP1);
    uint4 rg  = *reinterpret_cast<const uint4*>(gP);
    uint4 ru  = *reinterpret_cast<const uint4*>(uP);

    int kc = lane >> 4, mr = lane & 15;
    for (int k0 = 0; k0 < K; k0 += 32) {
        __syncthreads();
        *reinterpret_cast<uint4*>(aW0) = ra0;
        *reinterpret_cast<uint4*>(aW1) = ra1;
        *reinterpret_cast<uint4*>(gW)  = rg;
        *reinterpret_cast<uint4*>(uW)  = ru;
        __syncthreads();
        if (k0 + 32 < K) {
            ra0 = *reinterpret_cast<const uint4*>(aP0 + k0 + 32);
            ra1 = *reinterpret_cast<const uint4*>(aP1 + k0 + 32);
            rg  = *reinterpret_cast<const uint4*>(gP + k0 + 32);
            ru  = *reinterpret_cast<const uint4*>(uP + k0 + 32);
        }
        bf16x8 af[2], gf[4], uf[4];
        #pragma unroll
        for (int mi = 0; mi < 2; ++mi)
            af[mi] = *reinterpret_cast<const bf16x8*>(&As[kc * 1024 + (wave * 32 + mi * 16 + mr) * 8]);
        #pragma unroll
        for (int ni = 0; ni < 4; ++ni) {
            gf[ni] = *reinterpret_cast<const bf16x8*>(&Gs[kc * 512 + (ni * 16 + mr) * 8]);
            uf[ni] = *reinterpret_cast<const bf16x8*>(&Us[kc * 512 + (ni * 16 + mr) * 8]);
        }
        #pragma unroll
        for (int mi = 0; mi < 2; ++mi)
            #pragma unroll
            for (int ni = 0; ni < 4; ++ni) {
                accg[mi][ni] = __builtin_amdgcn_mfma_f32_16x16x32_bf16(af[mi], gf[ni], accg[mi][ni], 0, 0, 0);
                accu[mi][ni] = __builtin_amdgcn_mfma_f32_16x16x32_bf16(af[mi], uf[ni], accu[mi][ni], 0, 0, 0);
            }
    }
    int quad = lane >> 4;
    #pragma unroll
    for (int mi = 0; mi < 2; ++mi) {
        int rb = m0 + wave * 32 + mi * 16 + quad * 4;
        #pragma unroll
        for (int ni = 0; ni < 4; ++ni)
            #pragma unroll
            for (int r = 0; r < 4; ++r) {
                float g = accg[mi][ni][r];
                float gl = 0.5f * g * (1.f + tanhf(0.7978845608028654f * (g + 0.044715f * g * g * g)));
                float val = gl * accu[mi][ni][r];
                Cbf[(size_t)(rb + r) * N + n0 + ni * 16 + mr] = f2bf(val);
            }
    }
}

// ---------------- per-head LN (+optional RoPE), strided input -------------------
__global__ __launch_bounds__(256) void qkv_norm_rope(
    const float* __restrict__ in, const float* __restrict__ w,
    const float* __restrict__ cs, const float* __restrict__ sn,
    float* __restrict__ out, int nh, int do_rope, int stride, int base)
{
    int blk = blockIdx.x;
    int h = blk % nh;
    int trow = blk / nh;
    int b = trow / T_;
    int t = trow % T_;
    int d = threadIdx.x;
    float x = in[(size_t)trow * stride + base + h * HD_ + d];
    float mu = block_sum(x) * (1.f / HD_);
    float xc = x - mu;
    float var = block_sum(xc * xc) * (1.f / HD_);
    float n = xc * rsqrtf(var + EPS_) * (w ? w[d] : 1.f);
    __shared__ float buf[HD_];
    buf[d] = n;
    __syncthreads();
    float val = n;
    if (do_rope) {
        float c = cs[(size_t)trow * HD_ + d];
        float s = sn[(size_t)trow * HD_ + d];
        float other = (d < 128) ? -buf[d + 128] : buf[d - 128];
        val = n * c + other * s;
    }
    out[(((size_t)b * nh + h) * T_ + t) * HD_ + d] = val;
}

// ---------------- causal attention, one block per (b,h,q-row), bf16 out ---------
__global__ __launch_bounds__(256) void attn_kernel(
    const float* __restrict__ qt, const float* __restrict__ kt,
    const float* __restrict__ vt, unsigned short* __restrict__ out)
{
    int blk = blockIdx.x;
    int qi = blk % T_;
    int bh = blk / T_;
    int h = bh % NH_;
    int b = bh / NH_;
    int kvh = h >> 2;
    int tid = threadIdx.x;
    __shared__ float qs[HD_];
    __shared__ float sc[T_];
    __shared__ float ks[32][257];
    __shared__ float red[8][32];
    const float* qrow = qt + (((size_t)b * NH_ + h) * T_ + qi) * HD_;
    qs[tid] = qrow[tid];
    const float* Kb = kt + ((size_t)b * NKV_ + kvh) * T_ * HD_;
    const float* Vb = vt + ((size_t)b * NKV_ + kvh) * T_ * HD_;
    int L = qi + 1;
    __syncthreads();

    for (int kb = 0; kb < L; kb += 32) {
        int rows = min(32, L - kb);
        for (int u = 0; u < 32; ++u)
            if (u < rows) ks[u][tid] = Kb[(size_t)(kb + u) * HD_ + tid];
        __syncthreads();
        int kl = tid & 31, ch = tid >> 5;
        float p = 0.f;
        if (kl < rows) {
            #pragma unroll
            for (int i = 0; i < 32; ++i) p += qs[ch * 32 + i] * ks[kl][ch * 32 + i];
        }
        red[ch][kl] = p;
        __syncthreads();
        if (tid < rows) {
            float s = 0.f;
            #pragma unroll
            for (int c = 0; c < 8; ++c) s += red[c][tid];
            sc[kb + tid] = s;
        }
        __syncthreads();
    }

    float mx = -3.402823466e38f;
    for (int k2 = tid; k2 < L; k2 += 256) mx = fmaxf(mx, sc[k2]);
    mx = block_max(mx);
    float sm = 0.f;
    for (int k2 = tid; k2 < L; k2 += 256) { float e = expf(sc[k2] - mx); sc[k2] = e; sm += e; }
    sm = block_sum(sm);
    float inv = 1.f / sm;
    float acc = 0.f;
    for (int k2 = 0; k2 < L; ++k2) acc += sc[k2] * Vb[(size_t)k2 * HD_ + tid];
    out[(((size_t)b * T_ + qi) * NH_ + h) * HD_ + tid] = f2bf(acc * inv);
}

// ---------------- altup correct + output-scale on stream 0 ----------------------
__global__ __launch_bounds__(256) void correct_kernel(
    const float* __restrict__ act, const float* __restrict__ pred,
    const float* __restrict__ mc, const float* __restrict__ ccw,
    const float* __restrict__ cscale, float* __restrict__ out)
{
    size_t row = blockIdx.x;
    int tid = threadIdx.x;
    __shared__ float ms[4];
    __shared__ float cc[4];
    if (tid < 4) ms[tid] = mc[row * S_ + tid];
    __syncthreads();
    if (tid < 4) {
        float s = 1.f;
        #pragma unroll
        for (int i = 0; i < 4; ++i) s += ms[i] * ccw[tid * 4 + i];
        cc[tid] = s;
    }
    __syncthreads();
    const size_t STRIDE = (size_t)ROWS_ * H_;
    #pragma unroll
    for (int i = 0; i < 8; ++i) {
        size_t idx = row * H_ + i*256 + tid;
        float a  = act[idx];
        float p0 = pred[idx];
        float inn = a - p0;
        #pragma unroll
        for (int j = 0; j < 4; ++j) {
            float val = inn * cc[j] + pred[idx + (size_t)j * STRIDE];
            if (j == 0) val *= cscale[i*256 + tid];
            out[idx + (size_t)j * STRIDE] = val;
        }
    }
}

// ---------------- launcher ----------------
extern "C" void kernel_launch(void* const* d_in, const int* in_sizes, int n_in,
                              void* d_out, int out_size, void* d_ws, size_t ws_size,
                              hipStream_t stream)
{
    (void)in_sizes; (void)n_in; (void)out_size; (void)ws_size;
    const float* hidden         = (const float*)d_in[0];
    const float* cosp           = (const float*)d_in[1];
    const float* sinp           = (const float*)d_in[2];
    const float* wq             = (const float*)d_in[3];
    const float* wk             = (const float*)d_in[4];
    const float* wv             = (const float*)d_in[5];
    const float* wo             = (const float*)d_in[6];
    const float* q_norm_w       = (const float*)d_in[7];
    const float* k_norm_w       = (const float*)d_in[8];
    const float* input_ln_w     = (const float*)d_in[9];
    const float* post_attn_ln_w = (const float*)d_in[10];
    const float* pre_ffw_ln_w   = (const float*)d_in[11];
    const float* post_ffw_ln_w  = (const float*)d_in[12];
    const float* gate_w         = (const float*)d_in[13];
    const float* up_w           = (const float*)d_in[14];
    const float* down_w         = (const float*)d_in[15];
    const float* ll_w           = (const float*)d_in[16];
    const float* lr_w           = (const float*)d_in[17];
    const float* laurel_norm_w  = (const float*)d_in[18];
    const float* router_norm_w  = (const float*)d_in[19];
    const float* router_w       = (const float*)d_in[20];
    const float* pred_coef_w    = (const float*)d_in[21];
    const float* corr_coef_w    = (const float*)d_in[22];
    const float* cscale         = (const float*)d_in[23];
    float* outp = (float*)d_out;

    char* base = (char*)d_ws;
    float* pred   = (float*)base;              base += 67108864;   // [4,R,H] fp32
    float* xnorm  = (float*)base;              base += 16777216;
    unsigned short* xnorm_bf = (unsigned short*)base; base += 8388608;
    float* lout   = (float*)base;              base += 16777216;
    float* alaur  = (float*)base;              base += 16777216;
    float* tmpH   = (float*)base;              base += 16777216;
    float* mbuf   = (float*)base;              base += 32768;
    float* mcbuf  = (float*)base;              base += 32768;
    float* ltmp   = (float*)base;              base += 524288;
    char* arena = base;                        // 100,663,296 B
    // attention phase layout
    unsigned short* qkvw_bf = (unsigned short*)arena;
    float* qkv_pre = (float*)(arena + 12582912);
    float* q_t     = (float*)(arena + 37748736);
    float* k_t     = (float*)(arena + 54525952);
    float* v_t     = (float*)(arena + 58720256);
    unsigned short* wo_bf   = (unsigned short*)(arena + 62914560);
    unsigned short* attn_bf = (unsigned short*)(arena + 71303168);
    // MLP phase layout (aliases attention phase)
    unsigned short* gate_bf = (unsigned short*)arena;
    unsigned short* up_bf   = (unsigned short*)(arena + 33554432);
    unsigned short* gu_bf   = (unsigned short*)(arena + 67108864);
    unsigned short* down_bf = gate_bf;
    float* activated = lout;

    // ---- AltUp predict ----
    router_kernel <<<ROWS_, 256, 0, stream>>>(hidden, router_norm_w, router_w, mbuf);
    predict_kernel<<<ROWS_, 256, 0, stream>>>(hidden, mbuf, pred_coef_w, pred);
    ln_residual   <<<ROWS_, 256, 0, stream>>>(pred, input_ln_w, nullptr, nullptr, 1.f, xnorm, xnorm_bf);

    // ---- Laurel (fp32, small) ----
    gemm_nt<<<dim3(LR_/BN, ROWS_/BM), 256, 0, stream>>>(xnorm, ll_w, ltmp, ROWS_, LR_, H_);
    gemm_nt<<<dim3(H_/BN,  ROWS_/BM), 256, 0, stream>>>(ltmp, lr_w, tmpH, ROWS_, H_, LR_);
    ln_residual<<<ROWS_, 256, 0, stream>>>(tmpH, laurel_norm_w, xnorm, nullptr, 1.f, lout, nullptr);

    // ---- Attention ----
    cvt_bf16<<<2048, 256, 0, stream>>>(wq, qkvw_bf,            4194304);
    cvt_bf16<<< 512, 256, 0, stream>>>(wk, qkvw_bf + 4194304,  1048576);
    cvt_bf16<<< 512, 256, 0, stream>>>(wv, qkvw_bf + 5242880,  1048576);
    gemm_bf16nt<<<dim3(24, 16), 256, 0, stream>>>(xnorm_bf, qkvw_bf, qkv_pre, ROWS_, 3072, H_);
    qkv_norm_rope<<<ROWS_*NH_,  256, 0, stream>>>(qkv_pre, q_norm_w, cosp, sinp, q_t, NH_,  1, 3072, 0);
    qkv_norm_rope<<<ROWS_*NKV_, 256, 0, stream>>>(qkv_pre, k_norm_w, cosp, sinp, k_t, NKV_, 1, 3072, 2048);
    qkv_norm_rope<<<ROWS_*NKV_, 256, 0, stream>>>(qkv_pre, nullptr,  cosp, sinp, v_t, NKV_, 0, 3072, 2560);
    attn_kernel<<<B_*NH_*T_, 256, 0, stream>>>(q_t, k_t, v_t, attn_bf);
    cvt_bf16<<<2048, 256, 0, stream>>>(wo, wo_bf, 4194304);
    gemm_bf16nt<<<dim3(16, 16), 256, 0, stream>>>(attn_bf, wo_bf, tmpH, ROWS_, H_, NH_*HD_);
    ln_residual<<<ROWS_, 256, 0, stream>>>(tmpH, post_attn_ln_w, pred, lout, 0.7071067811865475f, alaur, nullptr);

    // ---- MLP ----
    ln_residual<<<ROWS_, 256, 0, stream>>>(alaur, pre_ffw_ln_w, nullptr, nullptr, 1.f, nullptr, xnorm_bf);
    cvt_bf16<<<8192, 256, 0, stream>>>(gate_w, gate_bf, 16777216);
    cvt_bf16<<<8192, 256, 0, stream>>>(up_w,   up_bf,   16777216);
    gemm_gateup_bf16<<<dim3(128, 16), 256, 0, stream>>>(xnorm_bf, gate_bf, up_bf, gu_bf, ROWS_, FF_, H_);
    cvt_bf16<<<8192, 256, 0, stream>>>(down_w, down_bf, 16777216);
    gemm_bf16nt<<<dim3(16, 16), 256, 0, stream>>>(gu_bf, down_bf, tmpH, ROWS_, H_, FF_);
    ln_residual<<<ROWS_, 256, 0, stream>>>(tmpH, post_ffw_ln_w, alaur, nullptr, 1.f, activated, nullptr);

    // ---- AltUp correct ----
    router_kernel <<<ROWS_, 256, 0, stream>>>(activated, router_norm_w, router_w, mcbuf);
    correct_kernel<<<ROWS_, 256, 0, stream>>>(activated, pred, mcbuf, corr_coef_w, cscale, outp);
}